// Round 1
// baseline (4911.242 us; speedup 1.0000x reference)
//
#include <hip/hip_runtime.h>
#include <cmath>

#define GS_LOOP(i, n) for (int i = blockIdx.x * blockDim.x + threadIdx.x; i < (n); i += gridDim.x * blockDim.x)

constexpr int NUSERS = 50000;
constexpr int NNODES = 100000;
constexpr int EMBD   = 128;
constexpr int NEDGE  = 2000000;

// ---------------- init: ego0 = concat(user, item); A = 1.0 ----------------
__global__ void init_k(const float* __restrict__ ue, const float* __restrict__ ie,
                       float* __restrict__ ego0, float* __restrict__ A) {
  const int NU4 = NUSERS * EMBD / 4;   // 1.6M float4
  const int NT4 = NNODES * EMBD / 4;   // 3.2M float4
  const float4* u4 = (const float4*)ue;
  const float4* i4 = (const float4*)ie;
  float4* e4 = (float4*)ego0;
  GS_LOOP(i, NT4) e4[i] = (i < NU4) ? u4[i] : i4[i - NU4];
  float4* A4 = (float4*)A;             // 4*NEDGE floats = NEDGE float4
  const float4 ones = make_float4(1.f, 1.f, 1.f, 1.f);
  GS_LOOP(i, NEDGE) A4[i] = ones;
}

// ---------------- CSR build ----------------
__global__ void hist_k(const int* __restrict__ h, int* __restrict__ counts) {
  GS_LOOP(e, NEDGE) atomicAdd(&counts[h[e]], 1);
}

__global__ __launch_bounds__(1024) void scan_k(const int* __restrict__ counts,
                                               int* __restrict__ row_ptr) {
  __shared__ int wsum[16];
  __shared__ int carry_s;
  const int tid = threadIdx.x;
  const int lane = tid & 63;
  const int wid = tid >> 6;
  if (tid == 0) { carry_s = 0; row_ptr[0] = 0; }
  __syncthreads();
  for (int base = 0; base < NNODES; base += 1024) {
    int i = base + tid;
    int v = (i < NNODES) ? counts[i] : 0;
    #pragma unroll
    for (int off = 1; off < 64; off <<= 1) {
      int y = __shfl_up(v, off, 64);
      if (lane >= off) v += y;
    }
    if (lane == 63) wsum[wid] = v;
    __syncthreads();
    if (wid == 0) {
      int w = (lane < 16) ? wsum[lane] : 0;
      #pragma unroll
      for (int off = 1; off < 16; off <<= 1) {
        int y = __shfl_up(w, off, 64);
        if (lane >= off) w += y;
      }
      if (lane < 16) wsum[lane] = w;
    }
    __syncthreads();
    int carry = carry_s;
    int incl = v + carry + (wid ? wsum[wid - 1] : 0);
    if (i < NNODES) row_ptr[i + 1] = incl;
    __syncthreads();
    if (tid == 1023) carry_s = incl;   // running total (OOB lanes contribute 0)
    __syncthreads();
  }
}

__global__ void fill_k(const int* __restrict__ h, const int* __restrict__ t,
                       const int* __restrict__ row_ptr, int* __restrict__ cur,
                       int* __restrict__ csr_t, int* __restrict__ csr_e) {
  GS_LOOP(e, NEDGE) {
    int u = h[e];
    int pos = row_ptr[u] + atomicAdd(&cur[u], 1);
    csr_t[pos] = t[e];
    csr_e[pos] = e;
  }
}

// ---------------- per-iteration: softmax(A) -> deg (atomic) ----------------
__global__ void deg_k(const float* __restrict__ A, const int* __restrict__ h,
                      float* __restrict__ deg) {
  const float4* A4 = (const float4*)A;
  GS_LOOP(e, NEDGE) {
    float4 a = A4[e];
    float m = fmaxf(fmaxf(a.x, a.y), fmaxf(a.z, a.w));
    float e0 = __expf(a.x - m), e1 = __expf(a.y - m);
    float e2 = __expf(a.z - m), e3 = __expf(a.w - m);
    float inv = 1.f / (e0 + e1 + e2 + e3);
    int u = h[e];
    atomicAdd(&deg[u * 4 + 0], e0 * inv);
    atomicAdd(&deg[u * 4 + 1], e1 * inv);
    atomicAdd(&deg[u * 4 + 2], e2 * inv);
    atomicAdd(&deg[u * 4 + 3], e3 * inv);
  }
}

__global__ void dinv_k(float* __restrict__ dv) {
  GS_LOOP(i, NNODES * 4) dv[i] = rsqrtf(fmaxf(dv[i], 1e-12f));
}

// ---------------- fused propagate + score update ----------------
// block = node u (owns all CSR edges with h==u), 128 threads = dims, f = d>>5
__global__ __launch_bounds__(128) void prop_score_k(
    const float* __restrict__ P, float* __restrict__ Q,
    const float* __restrict__ dv, const int* __restrict__ row_ptr,
    const int* __restrict__ csr_t, const int* __restrict__ csr_e,
    float* __restrict__ A, int do_score) {
  const int u = blockIdx.x;
  const int d = threadIdx.x;
  const int f = d >> 5;
  const int beg = row_ptr[u];
  const int end = row_ptr[u + 1];
  const float4* A4 = (const float4*)A;

  // loop 1: x[u] = d_inv[u] * sum_e v_e * d_inv[t_e] * P[t_e]
  float acc = 0.f;
  for (int p = beg; p < end; ++p) {
    const int tn = csr_t[p];
    const int eid = csr_e[p];
    float4 a = A4[eid];
    float m = fmaxf(fmaxf(a.x, a.y), fmaxf(a.z, a.w));
    float s0 = __expf(a.x - m), s1 = __expf(a.y - m);
    float s2 = __expf(a.z - m), s3 = __expf(a.w - m);
    float inv = 1.f / (s0 + s1 + s2 + s3);
    float v = (f == 0) ? s0 : (f == 1) ? s1 : (f == 2) ? s2 : s3;
    v *= inv;
    const float dt = dv[tn * 4 + f];
    acc += v * dt * P[tn * EMBD + d];
  }
  const float x = acc * dv[u * 4 + f];
  Q[u * EMBD + d] = x;
  if (!do_score) return;

  // chunk l2-norm of x over this 32-lane factor group
  float ss = x * x;
  #pragma unroll
  for (int m = 1; m < 32; m <<= 1) ss += __shfl_xor(ss, m, 64);
  const float xn = x * (1.f / fmaxf(sqrtf(ss), 1e-12f));

  // loop 2: A[e][f] += sum_d xn * tanh(l2norm(P[t] chunk))
  for (int p = beg; p < end; ++p) {
    const int tn = csr_t[p];
    const int eid = csr_e[p];
    const float y = P[tn * EMBD + d];
    float sy = y * y;
    #pragma unroll
    for (int m = 1; m < 32; m <<= 1) sy += __shfl_xor(sy, m, 64);
    const float yn = y * (1.f / fmaxf(sqrtf(sy), 1e-12f));
    float s = xn * tanhf(yn);
    #pragma unroll
    for (int m = 1; m < 32; m <<= 1) s += __shfl_xor(s, m, 64);
    if ((d & 31) == 0) A[eid * 4 + f] += s;   // block-exclusive, no atomic needed
  }
}

// ---------------- output: mean of (ego0, ego1, ego2) written twice ----------------
// ego2 lives in the SECOND half of d_out (layout-identical); read-before-write per elem
__global__ void out_k(const float* __restrict__ e0, const float* __restrict__ e1,
                      float* __restrict__ out) {
  const float4* a4 = (const float4*)e0;
  const float4* b4 = (const float4*)e1;
  float4* o1 = (float4*)out;
  float4* o2 = (float4*)(out + (size_t)NNODES * EMBD);
  GS_LOOP(i, NNODES * EMBD / 4) {
    float4 a = a4[i], b = b4[i], c = o2[i];
    float4 r = make_float4((a.x + b.x + c.x) * (1.f / 3.f),
                           (a.y + b.y + c.y) * (1.f / 3.f),
                           (a.z + b.z + c.z) * (1.f / 3.f),
                           (a.w + b.w + c.w) * (1.f / 3.f));
    o1[i] = r;
    o2[i] = r;
  }
}

extern "C" void kernel_launch(void* const* d_in, const int* in_sizes, int n_in,
                              void* d_out, int out_size, void* d_ws, size_t ws_size,
                              hipStream_t stream) {
  const float* ue = (const float*)d_in[0];
  const float* ie = (const float*)d_in[1];
  const int* h = (const int*)d_in[2];
  const int* t = (const int*)d_in[3];
  float* out = (float*)d_out;
  char* ws = (char*)d_ws;

  size_t off = 0;
  auto alloc = [&](size_t bytes) -> void* {
    void* p = ws + off;
    off += (bytes + 255) & ~size_t(255);
    return p;
  };
  float* ego0  = (float*)alloc(sizeof(float) * (size_t)NNODES * EMBD);  // 51.2 MB
  float* ego1  = (float*)alloc(sizeof(float) * (size_t)NNODES * EMBD);  // 51.2 MB
  float* A     = (float*)alloc(sizeof(float) * 4 * (size_t)NEDGE);      // 32  MB
  float* dv    = (float*)alloc(sizeof(float) * NNODES * 4);             // 1.6 MB
  int* row_ptr = (int*)alloc(sizeof(int) * (NNODES + 1));
  int* cur     = (int*)alloc(sizeof(int) * NNODES);
  int* csr_t   = (int*)alloc(sizeof(int) * NEDGE);                      // 8 MB
  int* csr_e   = (int*)alloc(sizeof(int) * NEDGE);                      // 8 MB
  float* ego2  = out + (size_t)NNODES * EMBD;  // second half of d_out

  // setup (once per call)
  init_k<<<2048, 256, 0, stream>>>(ue, ie, ego0, A);
  hipMemsetAsync(cur, 0, sizeof(int) * NNODES, stream);
  hist_k<<<2048, 256, 0, stream>>>(h, cur);
  scan_k<<<1, 1024, 0, stream>>>(cur, row_ptr);
  hipMemsetAsync(cur, 0, sizeof(int) * NNODES, stream);
  fill_k<<<2048, 256, 0, stream>>>(h, t, row_ptr, cur, csr_t, csr_e);

  // 2 layers x 2 routing iterations
  for (int pass = 0; pass < 4; ++pass) {
    const float* P = (pass < 2) ? ego0 : ego1;
    float* Q       = (pass < 2) ? ego1 : ego2;
    const int do_score = (pass == 3) ? 0 : 1;  // last A-update is dead in the reference
    hipMemsetAsync(dv, 0, sizeof(float) * NNODES * 4, stream);
    deg_k<<<2048, 256, 0, stream>>>(A, h, dv);
    dinv_k<<<(NNODES * 4 + 255) / 256, 256, 0, stream>>>(dv);
    prop_score_k<<<NNODES, 128, 0, stream>>>(P, Q, dv, row_ptr, csr_t, csr_e, A, do_score);
  }

  out_k<<<2048, 256, 0, stream>>>(ego0, ego1, out);
}

// Round 3
// 1812.360 us; speedup vs baseline: 2.7099x; 2.7099x over previous
//
#include <hip/hip_runtime.h>
#include <cmath>

#define GS_LOOP(i, n) for (int i = blockIdx.x * blockDim.x + threadIdx.x; i < (n); i += gridDim.x * blockDim.x)

constexpr int NUSERS = 50000;
constexpr int NNODES = 100000;
constexpr int EMBD   = 128;
constexpr int NEDGE  = 2000000;

// ---------------- init: ego0 = concat(user, item); A(csr-ordered) = 1.0 ----------------
__global__ void init_k(const float* __restrict__ ue, const float* __restrict__ ie,
                       float* __restrict__ ego0, float* __restrict__ A) {
  const int NU4 = NUSERS * EMBD / 4;
  const int NT4 = NNODES * EMBD / 4;
  const float4* u4 = (const float4*)ue;
  const float4* i4 = (const float4*)ie;
  float4* e4 = (float4*)ego0;
  GS_LOOP(i, NT4) e4[i] = (i < NU4) ? u4[i] : i4[i - NU4];
  float4* A4 = (float4*)A;
  const float4 ones = make_float4(1.f, 1.f, 1.f, 1.f);
  GS_LOOP(i, NEDGE) A4[i] = ones;
}

// ---------------- CSR build ----------------
__global__ void hist_k(const int* __restrict__ h, int* __restrict__ counts) {
  GS_LOOP(e, NEDGE) atomicAdd(&counts[h[e]], 1);
}

__global__ __launch_bounds__(1024) void scan_k(const int* __restrict__ counts,
                                               int* __restrict__ row_ptr) {
  __shared__ int wsum[16];
  __shared__ int carry_s;
  const int tid = threadIdx.x;
  const int lane = tid & 63;
  const int wid = tid >> 6;
  if (tid == 0) { carry_s = 0; row_ptr[0] = 0; }
  __syncthreads();
  for (int base = 0; base < NNODES; base += 1024) {
    int i = base + tid;
    int v = (i < NNODES) ? counts[i] : 0;
    #pragma unroll
    for (int off = 1; off < 64; off <<= 1) {
      int y = __shfl_up(v, off, 64);
      if (lane >= off) v += y;
    }
    if (lane == 63) wsum[wid] = v;
    __syncthreads();
    if (wid == 0) {
      int w = (lane < 16) ? wsum[lane] : 0;
      #pragma unroll
      for (int off = 1; off < 16; off <<= 1) {
        int y = __shfl_up(w, off, 64);
        if (lane >= off) w += y;
      }
      if (lane < 16) wsum[lane] = w;
    }
    __syncthreads();
    int carry = carry_s;
    int incl = v + carry + (wid ? wsum[wid - 1] : 0);
    if (i < NNODES) row_ptr[i + 1] = incl;
    __syncthreads();
    if (tid == 1023) carry_s = incl;
    __syncthreads();
  }
}

// edge identity is irrelevant downstream (A lives in CSR order), so store only t
__global__ void fill_k(const int* __restrict__ h, const int* __restrict__ t,
                       const int* __restrict__ row_ptr, int* __restrict__ cur,
                       int* __restrict__ csr_t) {
  GS_LOOP(e, NEDGE) {
    int u = h[e];
    int pos = row_ptr[u] + atomicAdd(&cur[u], 1);
    csr_t[pos] = t[e];
  }
}

// ---------------- per-pass: softmax(A)->c (csr order) + deg, no atomics ----------------
__global__ void deg_sm_k(const float* __restrict__ A, const int* __restrict__ row_ptr,
                         float* __restrict__ c, float* __restrict__ dv) {
  const float4* A4 = (const float4*)A;
  float4* c4 = (float4*)c;
  GS_LOOP(u, NNODES) {
    const int beg = row_ptr[u], end = row_ptr[u + 1];
    float d0 = 0.f, d1 = 0.f, d2 = 0.f, d3 = 0.f;
    for (int p = beg; p < end; ++p) {
      float4 a = A4[p];
      float m = fmaxf(fmaxf(a.x, a.y), fmaxf(a.z, a.w));
      float e0 = __expf(a.x - m), e1 = __expf(a.y - m);
      float e2 = __expf(a.z - m), e3 = __expf(a.w - m);
      float inv = 1.f / (e0 + e1 + e2 + e3);
      e0 *= inv; e1 *= inv; e2 *= inv; e3 *= inv;
      c4[p] = make_float4(e0, e1, e2, e3);
      d0 += e0; d1 += e1; d2 += e2; d3 += e3;
    }
    ((float4*)dv)[u] = make_float4(d0, d1, d2, d3);
  }
}

__global__ void dinv_k(float* __restrict__ dv) {
  GS_LOOP(i, NNODES * 4) dv[i] = 1.f / sqrtf(fmaxf(dv[i], 1e-12f));
}

// c[p][f] *= d_inv[t_p][f]
__global__ void scale_c_k(float* __restrict__ c, const int* __restrict__ csr_t,
                          const float* __restrict__ dv) {
  float4* c4 = (float4*)c;
  const float4* dv4 = (const float4*)dv;
  GS_LOOP(p, NEDGE) {
    float4 s = c4[p];
    float4 dt = dv4[csr_t[p]];
    c4[p] = make_float4(s.x * dt.x, s.y * dt.y, s.z * dt.z, s.w * dt.w);
  }
}

// ---------------- per-layer: Tn[n][d] = tanh(chunk_l2norm(P[n])[d]) ----------------
__global__ __launch_bounds__(256) void tanh_k(const float4* __restrict__ P4,
                                              float4* __restrict__ Tn4) {
  const int j = threadIdx.x & 31;                 // float4 column within row
  const int r0 = blockIdx.x * 8 + (threadIdx.x >> 5);
  for (int u = r0; u < NNODES; u += gridDim.x * 8) {
    float4 y = P4[(size_t)u * 32 + j];
    float ss = y.x * y.x + y.y * y.y + y.z * y.z + y.w * y.w;
    ss += __shfl_xor(ss, 1, 64);
    ss += __shfl_xor(ss, 2, 64);
    ss += __shfl_xor(ss, 4, 64);                  // reduce over 8-lane factor group
    float inv = 1.f / fmaxf(sqrtf(ss), 1e-12f);
    Tn4[(size_t)u * 32 + j] = make_float4(tanhf(y.x * inv), tanhf(y.y * inv),
                                          tanhf(y.z * inv), tanhf(y.w * inv));
  }
}

// ---------------- fused propagate + score update (wave per node, float4 lanes) ----------------
__global__ __launch_bounds__(256) void prop_k(
    const float4* __restrict__ P4, float4* __restrict__ Q4,
    const float* __restrict__ dv, const int* __restrict__ row_ptr,
    const int* __restrict__ csr_t, const float* __restrict__ c,
    const float4* __restrict__ Tn4, float* __restrict__ A, int do_score) {
  const int u = blockIdx.x * 4 + (threadIdx.x >> 6);
  const int l = threadIdx.x & 63;
  const int half = l >> 5;     // which of 2 edges per iteration
  const int j = l & 31;        // float4 column
  const int f = j >> 3;        // factor
  const int beg = row_ptr[u], end = row_ptr[u + 1];

  // loop 1: x[u] = d_inv[u] * sum_p c[p][f] * P[t_p]
  float4 acc = make_float4(0.f, 0.f, 0.f, 0.f);
  for (int p = beg + half; p < end; p += 2) {
    const int tn = csr_t[p];
    const float cf = c[(size_t)p * 4 + f];        // coalesced: 4 words / 32 lanes
    const float4 y = P4[(size_t)tn * 32 + j];     // gathered 512B row
    acc.x += cf * y.x; acc.y += cf * y.y; acc.z += cf * y.z; acc.w += cf * y.w;
  }
  acc.x += __shfl_xor(acc.x, 32, 64);
  acc.y += __shfl_xor(acc.y, 32, 64);
  acc.z += __shfl_xor(acc.z, 32, 64);
  acc.w += __shfl_xor(acc.w, 32, 64);
  const float du = dv[u * 4 + f];
  const float4 x = make_float4(acc.x * du, acc.y * du, acc.z * du, acc.w * du);
  if (half == 0) Q4[(size_t)u * 32 + j] = x;
  if (!do_score) return;

  // chunk l2-norm of x (8-lane factor group)
  float ss = x.x * x.x + x.y * x.y + x.z * x.z + x.w * x.w;
  ss += __shfl_xor(ss, 1, 64);
  ss += __shfl_xor(ss, 2, 64);
  ss += __shfl_xor(ss, 4, 64);
  const float inv = 1.f / fmaxf(sqrtf(ss), 1e-12f);
  const float4 xn = make_float4(x.x * inv, x.y * inv, x.z * inv, x.w * inv);

  // loop 2: A[p][f] += dot(xn_chunk, Tn[t]_chunk)   (sequential A writes, no atomics)
  for (int p = beg + half; p < end; p += 2) {
    const int tn = csr_t[p];
    const float4 tt = Tn4[(size_t)tn * 32 + j];
    float s = xn.x * tt.x + xn.y * tt.y + xn.z * tt.z + xn.w * tt.w;
    s += __shfl_xor(s, 1, 64);
    s += __shfl_xor(s, 2, 64);
    s += __shfl_xor(s, 4, 64);
    if ((j & 7) == 0) A[(size_t)p * 4 + f] += s;
  }
}

// ---------------- output: mean of (ego0, ego1, ego2) written twice ----------------
__global__ void out_k(const float* __restrict__ e0, const float* __restrict__ e1,
                      float* __restrict__ out) {
  const float4* a4 = (const float4*)e0;
  const float4* b4 = (const float4*)e1;
  float4* o1 = (float4*)out;
  float4* o2 = (float4*)(out + (size_t)NNODES * EMBD);
  GS_LOOP(i, NNODES * EMBD / 4) {
    float4 a = a4[i], b = b4[i], c = o2[i];
    float4 r = make_float4((a.x + b.x + c.x) * (1.f / 3.f),
                           (a.y + b.y + c.y) * (1.f / 3.f),
                           (a.z + b.z + c.z) * (1.f / 3.f),
                           (a.w + b.w + c.w) * (1.f / 3.f));
    o1[i] = r;
    o2[i] = r;
  }
}

extern "C" void kernel_launch(void* const* d_in, const int* in_sizes, int n_in,
                              void* d_out, int out_size, void* d_ws, size_t ws_size,
                              hipStream_t stream) {
  const float* ue = (const float*)d_in[0];
  const float* ie = (const float*)d_in[1];
  const int* h = (const int*)d_in[2];
  const int* t = (const int*)d_in[3];
  float* out = (float*)d_out;
  char* ws = (char*)d_ws;

  size_t off = 0;
  auto alloc = [&](size_t bytes) -> void* {
    void* p = ws + off;
    off += (bytes + 255) & ~size_t(255);
    return p;
  };
  float* ego0  = (float*)alloc(sizeof(float) * (size_t)NNODES * EMBD);  // 51.2 MB
  float* ego1  = (float*)alloc(sizeof(float) * (size_t)NNODES * EMBD);  // 51.2 MB
  float* A     = (float*)alloc(sizeof(float) * 4 * (size_t)NEDGE);      // 32  MB (CSR order)
  float* c     = (float*)alloc(sizeof(float) * 4 * (size_t)NEDGE);      // 32  MB (CSR order)
  float* dv    = (float*)alloc(sizeof(float) * NNODES * 4);             // 1.6 MB
  int* row_ptr = (int*)alloc(sizeof(int) * (NNODES + 1));
  int* cur     = (int*)alloc(sizeof(int) * NNODES);
  int* csr_t   = (int*)alloc(sizeof(int) * NEDGE);                      // 8 MB
  float* ego2  = out + (size_t)NNODES * EMBD;   // second half of d_out
  float* Tn    = out;                           // first half of d_out (dead until out_k)

  // setup (once per call)
  init_k<<<2048, 256, 0, stream>>>(ue, ie, ego0, A);
  hipMemsetAsync(cur, 0, sizeof(int) * NNODES, stream);
  hist_k<<<2048, 256, 0, stream>>>(h, cur);
  scan_k<<<1, 1024, 0, stream>>>(cur, row_ptr);
  hipMemsetAsync(cur, 0, sizeof(int) * NNODES, stream);
  fill_k<<<2048, 256, 0, stream>>>(h, t, row_ptr, cur, csr_t);

  // 2 layers x 2 routing iterations
  for (int pass = 0; pass < 4; ++pass) {
    const float* P = (pass < 2) ? ego0 : ego1;
    float* Q       = (pass < 2) ? ego1 : ego2;
    const int do_score = (pass == 3) ? 0 : 1;   // last A-update is dead in the reference
    deg_sm_k<<<512, 256, 0, stream>>>(A, row_ptr, c, dv);
    dinv_k<<<(NNODES * 4 + 255) / 256, 256, 0, stream>>>(dv);
    scale_c_k<<<2048, 256, 0, stream>>>(c, csr_t, dv);
    if (pass == 0 || pass == 2)   // Tn depends only on P, shared within a layer
      tanh_k<<<12500, 256, 0, stream>>>((const float4*)P, (float4*)Tn);
    prop_k<<<NNODES / 4, 256, 0, stream>>>((const float4*)P, (float4*)Q, dv, row_ptr,
                                           csr_t, c, (const float4*)Tn, A, do_score);
  }

  out_k<<<2048, 256, 0, stream>>>(ego0, ego1, out);
}

// Round 4
// 1663.485 us; speedup vs baseline: 2.9524x; 1.0895x over previous
//
#include <hip/hip_runtime.h>
#include <cmath>

#define GS_LOOP(i, n) for (int i = blockIdx.x * blockDim.x + threadIdx.x; i < (n); i += gridDim.x * blockDim.x)

constexpr int NUSERS = 50000;
constexpr int NNODES = 100000;
constexpr int EMBD   = 128;
constexpr int NEDGE  = 2000000;

// ---------------- init: ego0 = concat(user, item); A(csr-ordered) = 1.0 ----------------
__global__ void init_k(const float* __restrict__ ue, const float* __restrict__ ie,
                       float* __restrict__ ego0, float* __restrict__ A) {
  const int NU4 = NUSERS * EMBD / 4;
  const int NT4 = NNODES * EMBD / 4;
  const float4* u4 = (const float4*)ue;
  const float4* i4 = (const float4*)ie;
  float4* e4 = (float4*)ego0;
  GS_LOOP(i, NT4) e4[i] = (i < NU4) ? u4[i] : i4[i - NU4];
  float4* A4 = (float4*)A;
  const float4 ones = make_float4(1.f, 1.f, 1.f, 1.f);
  GS_LOOP(i, NEDGE) A4[i] = ones;
}

// ---------------- CSR build ----------------
__global__ void hist_k(const int* __restrict__ h, int* __restrict__ counts) {
  GS_LOOP(e, NEDGE) atomicAdd(&counts[h[e]], 1);
}

__global__ __launch_bounds__(1024) void scan_k(const int* __restrict__ counts,
                                               int* __restrict__ row_ptr) {
  __shared__ int wsum[16];
  __shared__ int carry_s;
  const int tid = threadIdx.x;
  const int lane = tid & 63;
  const int wid = tid >> 6;
  if (tid == 0) { carry_s = 0; row_ptr[0] = 0; }
  __syncthreads();
  for (int base = 0; base < NNODES; base += 1024) {
    int i = base + tid;
    int v = (i < NNODES) ? counts[i] : 0;
    #pragma unroll
    for (int off = 1; off < 64; off <<= 1) {
      int y = __shfl_up(v, off, 64);
      if (lane >= off) v += y;
    }
    if (lane == 63) wsum[wid] = v;
    __syncthreads();
    if (wid == 0) {
      int w = (lane < 16) ? wsum[lane] : 0;
      #pragma unroll
      for (int off = 1; off < 16; off <<= 1) {
        int y = __shfl_up(w, off, 64);
        if (lane >= off) w += y;
      }
      if (lane < 16) wsum[lane] = w;
    }
    __syncthreads();
    int carry = carry_s;
    int incl = v + carry + (wid ? wsum[wid - 1] : 0);
    if (i < NNODES) row_ptr[i + 1] = incl;
    __syncthreads();
    if (tid == 1023) carry_s = incl;
    __syncthreads();
  }
}

// edge identity is irrelevant downstream (A lives in CSR order), so store only t
__global__ void fill_k(const int* __restrict__ h, const int* __restrict__ t,
                       const int* __restrict__ row_ptr, int* __restrict__ cur,
                       int* __restrict__ csr_t) {
  GS_LOOP(e, NEDGE) {
    int u = h[e];
    int pos = row_ptr[u] + atomicAdd(&cur[u], 1);
    csr_t[pos] = t[e];
  }
}

// ---------------- per-pass: softmax(A)->c (csr order) + deg, 16 lanes per node ----------------
__global__ __launch_bounds__(256) void deg_sm_k(const float* __restrict__ A,
                                                const int* __restrict__ row_ptr,
                                                float* __restrict__ c,
                                                float* __restrict__ dv) {
  const float4* A4 = (const float4*)A;
  float4* c4 = (float4*)c;
  const int g = threadIdx.x >> 4;        // 16 node-groups per block
  const int lane16 = threadIdx.x & 15;
  const int u = blockIdx.x * 16 + g;
  if (u >= NNODES) return;
  const int beg = row_ptr[u], end = row_ptr[u + 1];
  float4 acc = make_float4(0.f, 0.f, 0.f, 0.f);
  for (int p = beg + lane16; p < end; p += 16) {
    float4 a = A4[p];
    float m = fmaxf(fmaxf(a.x, a.y), fmaxf(a.z, a.w));
    float e0 = __expf(a.x - m), e1 = __expf(a.y - m);
    float e2 = __expf(a.z - m), e3 = __expf(a.w - m);
    float inv = 1.f / (e0 + e1 + e2 + e3);
    float4 s = make_float4(e0 * inv, e1 * inv, e2 * inv, e3 * inv);
    c4[p] = s;
    acc.x += s.x; acc.y += s.y; acc.z += s.z; acc.w += s.w;
  }
  #pragma unroll
  for (int m = 1; m < 16; m <<= 1) {
    acc.x += __shfl_xor(acc.x, m, 64);
    acc.y += __shfl_xor(acc.y, m, 64);
    acc.z += __shfl_xor(acc.z, m, 64);
    acc.w += __shfl_xor(acc.w, m, 64);
  }
  if (lane16 == 0) ((float4*)dv)[u] = acc;
}

__global__ void dinv_k(float* __restrict__ dv) {
  GS_LOOP(i, NNODES * 4) dv[i] = 1.f / sqrtf(fmaxf(dv[i], 1e-12f));
}

// c[p][f] *= d_inv[t_p][f]
__global__ void scale_c_k(float* __restrict__ c, const int* __restrict__ csr_t,
                          const float* __restrict__ dv) {
  float4* c4 = (float4*)c;
  const float4* dv4 = (const float4*)dv;
  GS_LOOP(p, NEDGE) {
    float4 s = c4[p];
    float4 dt = dv4[csr_t[p]];
    c4[p] = make_float4(s.x * dt.x, s.y * dt.y, s.z * dt.z, s.w * dt.w);
  }
}

// ---------------- per-layer: Tn[n][d] = tanh(chunk_l2norm(P[n])[d]) ----------------
__global__ __launch_bounds__(256) void tanh_k(const float4* __restrict__ P4,
                                              float4* __restrict__ Tn4) {
  const int j = threadIdx.x & 31;                 // float4 column within row
  const int r0 = blockIdx.x * 8 + (threadIdx.x >> 5);
  for (int u = r0; u < NNODES; u += gridDim.x * 8) {
    float4 y = P4[(size_t)u * 32 + j];
    float ss = y.x * y.x + y.y * y.y + y.z * y.z + y.w * y.w;
    ss += __shfl_xor(ss, 1, 64);
    ss += __shfl_xor(ss, 2, 64);
    ss += __shfl_xor(ss, 4, 64);                  // reduce over 8-lane factor group
    float inv = 1.f / fmaxf(sqrtf(ss), 1e-12f);
    Tn4[(size_t)u * 32 + j] = make_float4(tanhf(y.x * inv), tanhf(y.y * inv),
                                          tanhf(y.z * inv), tanhf(y.w * inv));
  }
}

// ---------------- fused propagate + score update (wave per node, float4 lanes) ----------------
__global__ __launch_bounds__(256) void prop_k(
    const float4* __restrict__ P4, float4* __restrict__ Q4,
    const float* __restrict__ dv, const int* __restrict__ row_ptr,
    const int* __restrict__ csr_t, const float* __restrict__ c,
    const float4* __restrict__ Tn4, float* __restrict__ A, int do_score) {
  const int u = blockIdx.x * 4 + (threadIdx.x >> 6);
  const int l = threadIdx.x & 63;
  const int half = l >> 5;     // which of 2 edges per iteration
  const int j = l & 31;        // float4 column
  const int f = j >> 3;        // factor
  const int beg = row_ptr[u], end = row_ptr[u + 1];

  // loop 1: x[u] = d_inv[u] * sum_p c[p][f] * P[t_p]
  float4 acc = make_float4(0.f, 0.f, 0.f, 0.f);
  #pragma unroll 4
  for (int p = beg + half; p < end; p += 2) {
    const int tn = csr_t[p];
    const float cf = c[(size_t)p * 4 + f];        // coalesced: 4 words / 32 lanes
    const float4 y = P4[(size_t)tn * 32 + j];     // gathered 512B row
    acc.x += cf * y.x; acc.y += cf * y.y; acc.z += cf * y.z; acc.w += cf * y.w;
  }
  acc.x += __shfl_xor(acc.x, 32, 64);
  acc.y += __shfl_xor(acc.y, 32, 64);
  acc.z += __shfl_xor(acc.z, 32, 64);
  acc.w += __shfl_xor(acc.w, 32, 64);
  const float du = dv[u * 4 + f];
  const float4 x = make_float4(acc.x * du, acc.y * du, acc.z * du, acc.w * du);
  if (half == 0) Q4[(size_t)u * 32 + j] = x;
  if (!do_score) return;

  // chunk l2-norm of x (8-lane factor group)
  float ss = x.x * x.x + x.y * x.y + x.z * x.z + x.w * x.w;
  ss += __shfl_xor(ss, 1, 64);
  ss += __shfl_xor(ss, 2, 64);
  ss += __shfl_xor(ss, 4, 64);
  const float inv = 1.f / fmaxf(sqrtf(ss), 1e-12f);
  const float4 xn = make_float4(x.x * inv, x.y * inv, x.z * inv, x.w * inv);

  // loop 2: A[p][f] += dot(xn_chunk, Tn[t]_chunk)   (sequential A writes, no atomics)
  #pragma unroll 4
  for (int p = beg + half; p < end; p += 2) {
    const int tn = csr_t[p];
    const float4 tt = Tn4[(size_t)tn * 32 + j];
    float s = xn.x * tt.x + xn.y * tt.y + xn.z * tt.z + xn.w * tt.w;
    s += __shfl_xor(s, 1, 64);
    s += __shfl_xor(s, 2, 64);
    s += __shfl_xor(s, 4, 64);
    if ((j & 7) == 0) A[(size_t)p * 4 + f] += s;
  }
}

// ---------------- output: mean of (ego0, ego1, ego2) written twice ----------------
__global__ void out_k(const float* __restrict__ e0, const float* __restrict__ e1,
                      float* __restrict__ out) {
  const float4* a4 = (const float4*)e0;
  const float4* b4 = (const float4*)e1;
  float4* o1 = (float4*)out;
  float4* o2 = (float4*)(out + (size_t)NNODES * EMBD);
  GS_LOOP(i, NNODES * EMBD / 4) {
    float4 a = a4[i], b = b4[i], c = o2[i];
    float4 r = make_float4((a.x + b.x + c.x) * (1.f / 3.f),
                           (a.y + b.y + c.y) * (1.f / 3.f),
                           (a.z + b.z + c.z) * (1.f / 3.f),
                           (a.w + b.w + c.w) * (1.f / 3.f));
    o1[i] = r;
    o2[i] = r;
  }
}

extern "C" void kernel_launch(void* const* d_in, const int* in_sizes, int n_in,
                              void* d_out, int out_size, void* d_ws, size_t ws_size,
                              hipStream_t stream) {
  const float* ue = (const float*)d_in[0];
  const float* ie = (const float*)d_in[1];
  const int* h = (const int*)d_in[2];
  const int* t = (const int*)d_in[3];
  float* out = (float*)d_out;
  char* ws = (char*)d_ws;

  size_t off = 0;
  auto alloc = [&](size_t bytes) -> void* {
    void* p = ws + off;
    off += (bytes + 255) & ~size_t(255);
    return p;
  };
  float* ego0  = (float*)alloc(sizeof(float) * (size_t)NNODES * EMBD);  // 51.2 MB
  float* ego1  = (float*)alloc(sizeof(float) * (size_t)NNODES * EMBD);  // 51.2 MB
  float* A     = (float*)alloc(sizeof(float) * 4 * (size_t)NEDGE);      // 32  MB (CSR order)
  float* c     = (float*)alloc(sizeof(float) * 4 * (size_t)NEDGE);      // 32  MB (CSR order)
  float* dv    = (float*)alloc(sizeof(float) * NNODES * 4);             // 1.6 MB
  int* row_ptr = (int*)alloc(sizeof(int) * (NNODES + 1));
  int* cur     = (int*)alloc(sizeof(int) * NNODES);
  int* csr_t   = (int*)alloc(sizeof(int) * NEDGE);                      // 8 MB
  float* ego2  = out + (size_t)NNODES * EMBD;   // second half of d_out
  float* Tn    = out;                           // first half of d_out (dead until out_k)

  // setup (once per call)
  init_k<<<2048, 256, 0, stream>>>(ue, ie, ego0, A);
  hipMemsetAsync(cur, 0, sizeof(int) * NNODES, stream);
  hist_k<<<2048, 256, 0, stream>>>(h, cur);
  scan_k<<<1, 1024, 0, stream>>>(cur, row_ptr);
  hipMemsetAsync(cur, 0, sizeof(int) * NNODES, stream);
  fill_k<<<2048, 256, 0, stream>>>(h, t, row_ptr, cur, csr_t);

  // 2 layers x 2 routing iterations
  for (int pass = 0; pass < 4; ++pass) {
    const float* P = (pass < 2) ? ego0 : ego1;
    float* Q       = (pass < 2) ? ego1 : ego2;
    const int do_score = (pass == 3) ? 0 : 1;   // last A-update is dead in the reference
    deg_sm_k<<<(NNODES + 15) / 16, 256, 0, stream>>>(A, row_ptr, c, dv);
    dinv_k<<<(NNODES * 4 + 255) / 256, 256, 0, stream>>>(dv);
    scale_c_k<<<2048, 256, 0, stream>>>(c, csr_t, dv);
    if (pass == 0 || pass == 2)   // Tn depends only on P, shared within a layer
      tanh_k<<<12500, 256, 0, stream>>>((const float4*)P, (float4*)Tn);
    prop_k<<<NNODES / 4, 256, 0, stream>>>((const float4*)P, (float4*)Q, dv, row_ptr,
                                           csr_t, c, (const float4*)Tn, A, do_score);
  }

  out_k<<<2048, 256, 0, stream>>>(ego0, ego1, out);
}

// Round 5
// 1656.747 us; speedup vs baseline: 2.9644x; 1.0041x over previous
//
#include <hip/hip_runtime.h>
#include <cmath>

#define GS_LOOP(i, n) for (int i = blockIdx.x * blockDim.x + threadIdx.x; i < (n); i += gridDim.x * blockDim.x)

constexpr int NUSERS = 50000;
constexpr int NNODES = 100000;
constexpr int EMBD   = 128;
constexpr int NEDGE  = 2000000;

// ---------------- init: ego0 = concat(user, item); A(csr-ordered) = 1.0 ----------------
__global__ void init_k(const float* __restrict__ ue, const float* __restrict__ ie,
                       float* __restrict__ ego0, float* __restrict__ A) {
  const int NU4 = NUSERS * EMBD / 4;
  const int NT4 = NNODES * EMBD / 4;
  const float4* u4 = (const float4*)ue;
  const float4* i4 = (const float4*)ie;
  float4* e4 = (float4*)ego0;
  GS_LOOP(i, NT4) e4[i] = (i < NU4) ? u4[i] : i4[i - NU4];
  float4* A4 = (float4*)A;
  const float4 ones = make_float4(1.f, 1.f, 1.f, 1.f);
  GS_LOOP(i, NEDGE) A4[i] = ones;
}

// ---------------- CSR build ----------------
__global__ void hist_k(const int* __restrict__ h, int* __restrict__ counts) {
  GS_LOOP(e, NEDGE) atomicAdd(&counts[h[e]], 1);
}

__global__ __launch_bounds__(1024) void scan_k(const int* __restrict__ counts,
                                               int* __restrict__ row_ptr) {
  __shared__ int wsum[16];
  __shared__ int carry_s;
  const int tid = threadIdx.x;
  const int lane = tid & 63;
  const int wid = tid >> 6;
  if (tid == 0) { carry_s = 0; row_ptr[0] = 0; }
  __syncthreads();
  for (int base = 0; base < NNODES; base += 1024) {
    int i = base + tid;
    int v = (i < NNODES) ? counts[i] : 0;
    #pragma unroll
    for (int off = 1; off < 64; off <<= 1) {
      int y = __shfl_up(v, off, 64);
      if (lane >= off) v += y;
    }
    if (lane == 63) wsum[wid] = v;
    __syncthreads();
    if (wid == 0) {
      int w = (lane < 16) ? wsum[lane] : 0;
      #pragma unroll
      for (int off = 1; off < 16; off <<= 1) {
        int y = __shfl_up(w, off, 64);
        if (lane >= off) w += y;
      }
      if (lane < 16) wsum[lane] = w;
    }
    __syncthreads();
    int carry = carry_s;
    int incl = v + carry + (wid ? wsum[wid - 1] : 0);
    if (i < NNODES) row_ptr[i + 1] = incl;
    __syncthreads();
    if (tid == 1023) carry_s = incl;
    __syncthreads();
  }
}

// edge identity is irrelevant downstream (A lives in CSR order), so store only t
__global__ void fill_k(const int* __restrict__ h, const int* __restrict__ t,
                       const int* __restrict__ row_ptr, int* __restrict__ cur,
                       int* __restrict__ csr_t) {
  GS_LOOP(e, NEDGE) {
    int u = h[e];
    int pos = row_ptr[u] + atomicAdd(&cur[u], 1);
    csr_t[pos] = t[e];
  }
}

// ---------------- per-pass: softmax(A)->c (csr order) + d_inv, 16 lanes/node ----------------
__global__ __launch_bounds__(256) void deg_sm_k(const float* __restrict__ A,
                                                const int* __restrict__ row_ptr,
                                                float* __restrict__ c,
                                                float* __restrict__ dv) {
  const float4* A4 = (const float4*)A;
  float4* c4 = (float4*)c;
  const int g = threadIdx.x >> 4;
  const int lane16 = threadIdx.x & 15;
  const int u = blockIdx.x * 16 + g;
  if (u >= NNODES) return;
  const int beg = row_ptr[u], end = row_ptr[u + 1];
  float4 acc = make_float4(0.f, 0.f, 0.f, 0.f);
  for (int p = beg + lane16; p < end; p += 16) {
    float4 a = A4[p];
    float m = fmaxf(fmaxf(a.x, a.y), fmaxf(a.z, a.w));
    float e0 = __expf(a.x - m), e1 = __expf(a.y - m);
    float e2 = __expf(a.z - m), e3 = __expf(a.w - m);
    float inv = 1.f / (e0 + e1 + e2 + e3);
    float4 s = make_float4(e0 * inv, e1 * inv, e2 * inv, e3 * inv);
    c4[p] = s;
    acc.x += s.x; acc.y += s.y; acc.z += s.z; acc.w += s.w;
  }
  #pragma unroll
  for (int m = 1; m < 16; m <<= 1) {
    acc.x += __shfl_xor(acc.x, m, 64);
    acc.y += __shfl_xor(acc.y, m, 64);
    acc.z += __shfl_xor(acc.z, m, 64);
    acc.w += __shfl_xor(acc.w, m, 64);
  }
  if (lane16 == 0)
    ((float4*)dv)[u] = make_float4(rsqrtf(fmaxf(acc.x, 1e-12f)),
                                   rsqrtf(fmaxf(acc.y, 1e-12f)),
                                   rsqrtf(fmaxf(acc.z, 1e-12f)),
                                   rsqrtf(fmaxf(acc.w, 1e-12f)));
}

__device__ __forceinline__ float ftanh(float v) {
  // |v| <= 1 here; tanh(v) = 1 - 2/(exp(2v)+1)
  return 1.f - 2.f / (__expf(2.f * v) + 1.f);
}

// ---------------- fused propagate + score update (wave per node, float4 lanes) ----------------
// mode: 0 = score only (Q not written), 1 = score + write Q, 2 = no score, write mean output
__global__ __launch_bounds__(256) void prop_k(
    const float4* __restrict__ P4, float4* __restrict__ Q4,
    const float* __restrict__ dv, const int* __restrict__ row_ptr,
    const int* __restrict__ csr_t, const float* __restrict__ c,
    float* __restrict__ A, const float4* __restrict__ e0_4,
    const float4* __restrict__ e1_4, float4* __restrict__ o1_4,
    float4* __restrict__ o2_4, int mode) {
  const int u = blockIdx.x * 4 + (threadIdx.x >> 6);
  const int l = threadIdx.x & 63;
  const int half = l >> 5;     // which of 2 edges per iteration
  const int j = l & 31;        // float4 column
  const int f = j >> 3;        // factor
  const int beg = row_ptr[u], end = row_ptr[u + 1];

  // loop 1: x[u] = d_inv[u] * sum_p c[p][f] * d_inv[t_p][f] * P[t_p]
  float4 acc = make_float4(0.f, 0.f, 0.f, 0.f);
  int p = beg + half;
  for (; p + 6 < end; p += 8) {                // manual unroll x4: 4 gathers in flight
    const int t0 = csr_t[p],     t1 = csr_t[p + 2];
    const int t2 = csr_t[p + 4], t3 = csr_t[p + 6];
    const float c0 = c[(size_t)p * 4 + f]       * dv[t0 * 4 + f];
    const float c1 = c[(size_t)(p + 2) * 4 + f] * dv[t1 * 4 + f];
    const float c2 = c[(size_t)(p + 4) * 4 + f] * dv[t2 * 4 + f];
    const float c3 = c[(size_t)(p + 6) * 4 + f] * dv[t3 * 4 + f];
    const float4 y0 = P4[(size_t)t0 * 32 + j];
    const float4 y1 = P4[(size_t)t1 * 32 + j];
    const float4 y2 = P4[(size_t)t2 * 32 + j];
    const float4 y3 = P4[(size_t)t3 * 32 + j];
    acc.x += c0 * y0.x + c1 * y1.x + c2 * y2.x + c3 * y3.x;
    acc.y += c0 * y0.y + c1 * y1.y + c2 * y2.y + c3 * y3.y;
    acc.z += c0 * y0.z + c1 * y1.z + c2 * y2.z + c3 * y3.z;
    acc.w += c0 * y0.w + c1 * y1.w + c2 * y2.w + c3 * y3.w;
  }
  for (; p < end; p += 2) {                    // tail
    const int tn = csr_t[p];
    const float cf = c[(size_t)p * 4 + f] * dv[tn * 4 + f];
    const float4 y = P4[(size_t)tn * 32 + j];
    acc.x += cf * y.x; acc.y += cf * y.y; acc.z += cf * y.z; acc.w += cf * y.w;
  }
  acc.x += __shfl_xor(acc.x, 32, 64);
  acc.y += __shfl_xor(acc.y, 32, 64);
  acc.z += __shfl_xor(acc.z, 32, 64);
  acc.w += __shfl_xor(acc.w, 32, 64);
  const float du = dv[u * 4 + f];
  const float4 x = make_float4(acc.x * du, acc.y * du, acc.z * du, acc.w * du);

  if (mode == 2) {                             // final pass: write mean(e0,e1,x) to both halves
    if (half == 0) {
      const float4 a = e0_4[(size_t)u * 32 + j];
      const float4 b = e1_4[(size_t)u * 32 + j];
      const float4 r = make_float4((a.x + b.x + x.x) * (1.f / 3.f),
                                   (a.y + b.y + x.y) * (1.f / 3.f),
                                   (a.z + b.z + x.z) * (1.f / 3.f),
                                   (a.w + b.w + x.w) * (1.f / 3.f));
      o1_4[(size_t)u * 32 + j] = r;
      o2_4[(size_t)u * 32 + j] = r;
    }
    return;
  }
  if (mode == 1 && half == 0) Q4[(size_t)u * 32 + j] = x;

  // chunk l2-norm of x (8-lane factor group)
  float ss = x.x * x.x + x.y * x.y + x.z * x.z + x.w * x.w;
  ss += __shfl_xor(ss, 1, 64);
  ss += __shfl_xor(ss, 2, 64);
  ss += __shfl_xor(ss, 4, 64);
  const float inv = 1.f / fmaxf(sqrtf(ss), 1e-12f);
  const float4 xn = make_float4(x.x * inv, x.y * inv, x.z * inv, x.w * inv);

  // loop 2: A[p][f] += dot(xn_chunk, tanh(l2norm(P[t])_chunk))  (rows L2-warm from loop 1)
  #pragma unroll 2
  for (int q = beg + half; q < end; q += 2) {
    const int tn = csr_t[q];
    const float4 y = P4[(size_t)tn * 32 + j];
    float sy = y.x * y.x + y.y * y.y + y.z * y.z + y.w * y.w;
    sy += __shfl_xor(sy, 1, 64);
    sy += __shfl_xor(sy, 2, 64);
    sy += __shfl_xor(sy, 4, 64);
    const float yinv = 1.f / fmaxf(sqrtf(sy), 1e-12f);
    float s = xn.x * ftanh(y.x * yinv) + xn.y * ftanh(y.y * yinv) +
              xn.z * ftanh(y.z * yinv) + xn.w * ftanh(y.w * yinv);
    s += __shfl_xor(s, 1, 64);
    s += __shfl_xor(s, 2, 64);
    s += __shfl_xor(s, 4, 64);
    if ((j & 7) == 0) A[(size_t)q * 4 + f] += s;
  }
}

extern "C" void kernel_launch(void* const* d_in, const int* in_sizes, int n_in,
                              void* d_out, int out_size, void* d_ws, size_t ws_size,
                              hipStream_t stream) {
  const float* ue = (const float*)d_in[0];
  const float* ie = (const float*)d_in[1];
  const int* h = (const int*)d_in[2];
  const int* t = (const int*)d_in[3];
  float* out = (float*)d_out;
  char* ws = (char*)d_ws;

  size_t off = 0;
  auto alloc = [&](size_t bytes) -> void* {
    void* p = ws + off;
    off += (bytes + 255) & ~size_t(255);
    return p;
  };
  float* ego0  = (float*)alloc(sizeof(float) * (size_t)NNODES * EMBD);  // 51.2 MB
  float* ego1  = (float*)alloc(sizeof(float) * (size_t)NNODES * EMBD);  // 51.2 MB
  float* A     = (float*)alloc(sizeof(float) * 4 * (size_t)NEDGE);      // 32  MB (CSR order)
  float* c     = (float*)alloc(sizeof(float) * 4 * (size_t)NEDGE);      // 32  MB (CSR order)
  float* dv    = (float*)alloc(sizeof(float) * NNODES * 4);             // 1.6 MB
  int* row_ptr = (int*)alloc(sizeof(int) * (NNODES + 1));
  int* cur     = (int*)alloc(sizeof(int) * NNODES);
  int* csr_t   = (int*)alloc(sizeof(int) * NEDGE);                      // 8 MB
  float4* o1_4 = (float4*)out;
  float4* o2_4 = (float4*)(out + (size_t)NNODES * EMBD);

  // setup (once per call)
  init_k<<<2048, 256, 0, stream>>>(ue, ie, ego0, A);
  hipMemsetAsync(cur, 0, sizeof(int) * NNODES, stream);
  hist_k<<<2048, 256, 0, stream>>>(h, cur);
  scan_k<<<1, 1024, 0, stream>>>(cur, row_ptr);
  hipMemsetAsync(cur, 0, sizeof(int) * NNODES, stream);
  fill_k<<<2048, 256, 0, stream>>>(h, t, row_ptr, cur, csr_t);

  // 2 layers x 2 routing iterations
  // pass 0: P=ego0, score only            (Q dead: overwritten by pass 1)
  // pass 1: P=ego0, score + Q=ego1
  // pass 2: P=ego1, score only            (Q dead: overwritten by pass 3)
  // pass 3: P=ego1, mean output directly  (last A-update is dead in the reference)
  for (int pass = 0; pass < 4; ++pass) {
    const float* P = (pass < 2) ? ego0 : ego1;
    const int mode = (pass == 1) ? 1 : (pass == 3) ? 2 : 0;
    deg_sm_k<<<(NNODES + 15) / 16, 256, 0, stream>>>(A, row_ptr, c, dv);
    prop_k<<<NNODES / 4, 256, 0, stream>>>((const float4*)P, (float4*)ego1, dv, row_ptr,
                                           csr_t, c, A, (const float4*)ego0,
                                           (const float4*)ego1, o1_4, o2_4, mode);
  }
}

// Round 6
// 1247.743 us; speedup vs baseline: 3.9361x; 1.3278x over previous
//
#include <hip/hip_runtime.h>
#include <cmath>

#define GS_LOOP(i, n) for (int i = blockIdx.x * blockDim.x + threadIdx.x; i < (n); i += gridDim.x * blockDim.x)

constexpr int NUSERS = 50000;
constexpr int NNODES = 100000;
constexpr int EMBD   = 128;
constexpr int NEDGE  = 2000000;

__device__ __forceinline__ float bf2f(unsigned short u) {
  union { unsigned int i; float f; } v; v.i = ((unsigned int)u) << 16; return v.f;
}
__device__ __forceinline__ unsigned short f2bf(float x) {
  union { float f; unsigned int i; } v; v.f = x;
  unsigned int r = v.i + 0x7FFFu + ((v.i >> 16) & 1u);   // round to nearest even
  return (unsigned short)(r >> 16);
}

// ---------------- init: ego0 = concat(user, item); A(csr-ordered) = 1.0 ----------------
__global__ void init_k(const float* __restrict__ ue, const float* __restrict__ ie,
                       float* __restrict__ ego0, float* __restrict__ A) {
  const int NU4 = NUSERS * EMBD / 4;
  const int NT4 = NNODES * EMBD / 4;
  const float4* u4 = (const float4*)ue;
  const float4* i4 = (const float4*)ie;
  float4* e4 = (float4*)ego0;
  GS_LOOP(i, NT4) e4[i] = (i < NU4) ? u4[i] : i4[i - NU4];
  float4* A4 = (float4*)A;
  const float4 ones = make_float4(1.f, 1.f, 1.f, 1.f);
  GS_LOOP(i, NEDGE) A4[i] = ones;
}

// ---------------- CSR build ----------------
__global__ void hist_k(const int* __restrict__ h, int* __restrict__ counts) {
  GS_LOOP(e, NEDGE) atomicAdd(&counts[h[e]], 1);
}

__global__ __launch_bounds__(1024) void scan_k(const int* __restrict__ counts,
                                               int* __restrict__ row_ptr) {
  __shared__ int wsum[16];
  __shared__ int carry_s;
  const int tid = threadIdx.x;
  const int lane = tid & 63;
  const int wid = tid >> 6;
  if (tid == 0) { carry_s = 0; row_ptr[0] = 0; }
  __syncthreads();
  for (int base = 0; base < NNODES; base += 1024) {
    int i = base + tid;
    int v = (i < NNODES) ? counts[i] : 0;
    #pragma unroll
    for (int off = 1; off < 64; off <<= 1) {
      int y = __shfl_up(v, off, 64);
      if (lane >= off) v += y;
    }
    if (lane == 63) wsum[wid] = v;
    __syncthreads();
    if (wid == 0) {
      int w = (lane < 16) ? wsum[lane] : 0;
      #pragma unroll
      for (int off = 1; off < 16; off <<= 1) {
        int y = __shfl_up(w, off, 64);
        if (lane >= off) w += y;
      }
      if (lane < 16) wsum[lane] = w;
    }
    __syncthreads();
    int carry = carry_s;
    int incl = v + carry + (wid ? wsum[wid - 1] : 0);
    if (i < NNODES) row_ptr[i + 1] = incl;
    __syncthreads();
    if (tid == 1023) carry_s = incl;
    __syncthreads();
  }
}

// edge identity is irrelevant downstream (A lives in CSR order), so store only t
__global__ void fill_k(const int* __restrict__ h, const int* __restrict__ t,
                       const int* __restrict__ row_ptr, int* __restrict__ cur,
                       int* __restrict__ csr_t) {
  GS_LOOP(e, NEDGE) {
    int u = h[e];
    int pos = row_ptr[u] + atomicAdd(&cur[u], 1);
    csr_t[pos] = t[e];
  }
}

// ---------------- per-pass: softmax(A)->c (csr order) + d_inv, 16 lanes/node ----------------
__global__ __launch_bounds__(256) void deg_sm_k(const float* __restrict__ A,
                                                const int* __restrict__ row_ptr,
                                                float* __restrict__ c,
                                                float* __restrict__ dv) {
  const float4* A4 = (const float4*)A;
  float4* c4 = (float4*)c;
  const int g = threadIdx.x >> 4;
  const int lane16 = threadIdx.x & 15;
  const int u = blockIdx.x * 16 + g;
  if (u >= NNODES) return;
  const int beg = row_ptr[u], end = row_ptr[u + 1];
  float4 acc = make_float4(0.f, 0.f, 0.f, 0.f);
  for (int p = beg + lane16; p < end; p += 16) {
    float4 a = A4[p];
    float m = fmaxf(fmaxf(a.x, a.y), fmaxf(a.z, a.w));
    float e0 = __expf(a.x - m), e1 = __expf(a.y - m);
    float e2 = __expf(a.z - m), e3 = __expf(a.w - m);
    float inv = 1.f / (e0 + e1 + e2 + e3);
    float4 s = make_float4(e0 * inv, e1 * inv, e2 * inv, e3 * inv);
    c4[p] = s;
    acc.x += s.x; acc.y += s.y; acc.z += s.z; acc.w += s.w;
  }
  #pragma unroll
  for (int m = 1; m < 16; m <<= 1) {
    acc.x += __shfl_xor(acc.x, m, 64);
    acc.y += __shfl_xor(acc.y, m, 64);
    acc.z += __shfl_xor(acc.z, m, 64);
    acc.w += __shfl_xor(acc.w, m, 64);
  }
  if (lane16 == 0)
    ((float4*)dv)[u] = make_float4(rsqrtf(fmaxf(acc.x, 1e-12f)),
                                   rsqrtf(fmaxf(acc.y, 1e-12f)),
                                   rsqrtf(fmaxf(acc.z, 1e-12f)),
                                   rsqrtf(fmaxf(acc.w, 1e-12f)));
}

// ---------------- per-layer: Pb = bf16(P) ----------------
__global__ void conv_k(const float4* __restrict__ src, ushort4* __restrict__ dst) {
  GS_LOOP(i, NNODES * 32) {
    float4 a = src[i];
    dst[i] = make_ushort4(f2bf(a.x), f2bf(a.y), f2bf(a.z), f2bf(a.w));
  }
}

// ---------------- per-layer: Tnb[n][d] = bf16(tanh(chunk_l2norm(P[n])[d])) ----------------
__global__ __launch_bounds__(256) void tanh_k(const float4* __restrict__ P4,
                                              ushort4* __restrict__ Tnb4) {
  const int j = threadIdx.x & 31;
  const int r0 = blockIdx.x * 8 + (threadIdx.x >> 5);
  for (int u = r0; u < NNODES; u += gridDim.x * 8) {
    float4 y = P4[(size_t)u * 32 + j];
    float ss = y.x * y.x + y.y * y.y + y.z * y.z + y.w * y.w;
    ss += __shfl_xor(ss, 1, 64);
    ss += __shfl_xor(ss, 2, 64);
    ss += __shfl_xor(ss, 4, 64);                  // 8-lane factor-group reduce
    float inv = 1.f / fmaxf(sqrtf(ss), 1e-12f);
    Tnb4[(size_t)u * 32 + j] = make_ushort4(f2bf(tanhf(y.x * inv)), f2bf(tanhf(y.y * inv)),
                                            f2bf(tanhf(y.z * inv)), f2bf(tanhf(y.w * inv)));
  }
}

// ---------------- fused propagate + score update (wave per node, bf16 gathers) ----------------
// mode: 0 = score only, 1 = score + write Q(f32), 2 = no score, write mean to o1 only
__global__ __launch_bounds__(256) void prop_k(
    const ushort4* __restrict__ Pb4, float4* __restrict__ Q4,
    const float* __restrict__ dv, const int* __restrict__ row_ptr,
    const int* __restrict__ csr_t, const float* __restrict__ c,
    float* __restrict__ A, const ushort4* __restrict__ Tnb4,
    const float4* __restrict__ e0_4, const float4* __restrict__ e1_4,
    float4* __restrict__ o1_4, int mode) {
  const int u = blockIdx.x * 4 + (threadIdx.x >> 6);
  const int l = threadIdx.x & 63;
  const int half = l >> 5;     // which of 2 edges per iteration
  const int j = l & 31;        // float4 column
  const int f = j >> 3;        // factor
  const int beg = row_ptr[u], end = row_ptr[u + 1];

  // loop 1: x[u] = d_inv[u] * sum_p c[p][f] * d_inv[t_p][f] * Pb[t_p]
  float4 acc = make_float4(0.f, 0.f, 0.f, 0.f);
  int p = beg + half;
  for (; p + 6 < end; p += 8) {                // manual unroll x4: 4 row gathers in flight
    const int t0 = csr_t[p],     t1 = csr_t[p + 2];
    const int t2 = csr_t[p + 4], t3 = csr_t[p + 6];
    const float c0 = c[(size_t)p * 4 + f]       * dv[t0 * 4 + f];
    const float c1 = c[(size_t)(p + 2) * 4 + f] * dv[t1 * 4 + f];
    const float c2 = c[(size_t)(p + 4) * 4 + f] * dv[t2 * 4 + f];
    const float c3 = c[(size_t)(p + 6) * 4 + f] * dv[t3 * 4 + f];
    const ushort4 y0 = Pb4[(size_t)t0 * 32 + j];
    const ushort4 y1 = Pb4[(size_t)t1 * 32 + j];
    const ushort4 y2 = Pb4[(size_t)t2 * 32 + j];
    const ushort4 y3 = Pb4[(size_t)t3 * 32 + j];
    acc.x += c0 * bf2f(y0.x) + c1 * bf2f(y1.x) + c2 * bf2f(y2.x) + c3 * bf2f(y3.x);
    acc.y += c0 * bf2f(y0.y) + c1 * bf2f(y1.y) + c2 * bf2f(y2.y) + c3 * bf2f(y3.y);
    acc.z += c0 * bf2f(y0.z) + c1 * bf2f(y1.z) + c2 * bf2f(y2.z) + c3 * bf2f(y3.z);
    acc.w += c0 * bf2f(y0.w) + c1 * bf2f(y1.w) + c2 * bf2f(y2.w) + c3 * bf2f(y3.w);
  }
  for (; p < end; p += 2) {                    // tail
    const int tn = csr_t[p];
    const float cf = c[(size_t)p * 4 + f] * dv[tn * 4 + f];
    const ushort4 y = Pb4[(size_t)tn * 32 + j];
    acc.x += cf * bf2f(y.x); acc.y += cf * bf2f(y.y);
    acc.z += cf * bf2f(y.z); acc.w += cf * bf2f(y.w);
  }
  acc.x += __shfl_xor(acc.x, 32, 64);
  acc.y += __shfl_xor(acc.y, 32, 64);
  acc.z += __shfl_xor(acc.z, 32, 64);
  acc.w += __shfl_xor(acc.w, 32, 64);
  const float du = dv[u * 4 + f];
  const float4 x = make_float4(acc.x * du, acc.y * du, acc.z * du, acc.w * du);

  if (mode == 2) {                             // final pass: write mean(e0,e1,x) to o1
    if (half == 0) {
      const float4 a = e0_4[(size_t)u * 32 + j];
      const float4 b = e1_4[(size_t)u * 32 + j];
      o1_4[(size_t)u * 32 + j] = make_float4((a.x + b.x + x.x) * (1.f / 3.f),
                                             (a.y + b.y + x.y) * (1.f / 3.f),
                                             (a.z + b.z + x.z) * (1.f / 3.f),
                                             (a.w + b.w + x.w) * (1.f / 3.f));
    }
    return;
  }
  if (mode == 1 && half == 0) Q4[(size_t)u * 32 + j] = x;

  // chunk l2-norm of x (8-lane factor group)
  float ss = x.x * x.x + x.y * x.y + x.z * x.z + x.w * x.w;
  ss += __shfl_xor(ss, 1, 64);
  ss += __shfl_xor(ss, 2, 64);
  ss += __shfl_xor(ss, 4, 64);
  const float inv = 1.f / fmaxf(sqrtf(ss), 1e-12f);
  const float4 xn = make_float4(x.x * inv, x.y * inv, x.z * inv, x.w * inv);

  // loop 2: A[p][f] += dot(xn_chunk, Tnb[t]_chunk)  (sequential A writes, no atomics)
  int q = beg + half;
  for (; q + 2 < end; q += 4) {                // manual unroll x2
    const int t0 = csr_t[q], t1 = csr_t[q + 2];
    const ushort4 b0 = Tnb4[(size_t)t0 * 32 + j];
    const ushort4 b1 = Tnb4[(size_t)t1 * 32 + j];
    float s0 = xn.x * bf2f(b0.x) + xn.y * bf2f(b0.y) + xn.z * bf2f(b0.z) + xn.w * bf2f(b0.w);
    float s1 = xn.x * bf2f(b1.x) + xn.y * bf2f(b1.y) + xn.z * bf2f(b1.z) + xn.w * bf2f(b1.w);
    s0 += __shfl_xor(s0, 1, 64); s1 += __shfl_xor(s1, 1, 64);
    s0 += __shfl_xor(s0, 2, 64); s1 += __shfl_xor(s1, 2, 64);
    s0 += __shfl_xor(s0, 4, 64); s1 += __shfl_xor(s1, 4, 64);
    if ((j & 7) == 0) {
      A[(size_t)q * 4 + f] += s0;
      A[(size_t)(q + 2) * 4 + f] += s1;
    }
  }
  for (; q < end; q += 2) {                    // tail
    const int tn = csr_t[q];
    const ushort4 tb = Tnb4[(size_t)tn * 32 + j];
    float s = xn.x * bf2f(tb.x) + xn.y * bf2f(tb.y) + xn.z * bf2f(tb.z) + xn.w * bf2f(tb.w);
    s += __shfl_xor(s, 1, 64);
    s += __shfl_xor(s, 2, 64);
    s += __shfl_xor(s, 4, 64);
    if ((j & 7) == 0) A[(size_t)q * 4 + f] += s;
  }
}

extern "C" void kernel_launch(void* const* d_in, const int* in_sizes, int n_in,
                              void* d_out, int out_size, void* d_ws, size_t ws_size,
                              hipStream_t stream) {
  const float* ue = (const float*)d_in[0];
  const float* ie = (const float*)d_in[1];
  const int* h = (const int*)d_in[2];
  const int* t = (const int*)d_in[3];
  float* out = (float*)d_out;
  char* ws = (char*)d_ws;

  size_t off = 0;
  auto alloc = [&](size_t bytes) -> void* {
    void* p = ws + off;
    off += (bytes + 255) & ~size_t(255);
    return p;
  };
  float* ego0  = (float*)alloc(sizeof(float) * (size_t)NNODES * EMBD);  // 51.2 MB
  float* ego1  = (float*)alloc(sizeof(float) * (size_t)NNODES * EMBD);  // 51.2 MB
  float* A     = (float*)alloc(sizeof(float) * 4 * (size_t)NEDGE);      // 32  MB (CSR order)
  float* c     = (float*)alloc(sizeof(float) * 4 * (size_t)NEDGE);      // 32  MB (CSR order)
  float* dv    = (float*)alloc(sizeof(float) * NNODES * 4);             // 1.6 MB
  int* row_ptr = (int*)alloc(sizeof(int) * (NNODES + 1));
  int* cur     = (int*)alloc(sizeof(int) * NNODES);
  int* csr_t   = (int*)alloc(sizeof(int) * NEDGE);                      // 8 MB

  // bf16 gather tables live in d_out (each half = 51.2 MB = Pb(25.6) + Tnb(25.6)).
  // Layer-1 tables in o1 (dead by pass 3, which overwrites o1);
  // layer-2 tables in o2 (read during pass 3; o2 filled by the final d2d copy).
  float* o1 = out;
  float* o2 = out + (size_t)NNODES * EMBD;
  ushort4* Pb0  = (ushort4*)o1;
  ushort4* Tnb0 = (ushort4*)((char*)o1 + sizeof(unsigned short) * (size_t)NNODES * EMBD);
  ushort4* Pb1  = (ushort4*)o2;
  ushort4* Tnb1 = (ushort4*)((char*)o2 + sizeof(unsigned short) * (size_t)NNODES * EMBD);

  // setup (once per call)
  init_k<<<2048, 256, 0, stream>>>(ue, ie, ego0, A);
  hipMemsetAsync(cur, 0, sizeof(int) * NNODES, stream);
  hist_k<<<2048, 256, 0, stream>>>(h, cur);
  scan_k<<<1, 1024, 0, stream>>>(cur, row_ptr);
  hipMemsetAsync(cur, 0, sizeof(int) * NNODES, stream);
  fill_k<<<2048, 256, 0, stream>>>(h, t, row_ptr, cur, csr_t);

  conv_k<<<2048, 256, 0, stream>>>((const float4*)ego0, Pb0);
  tanh_k<<<12500, 256, 0, stream>>>((const float4*)ego0, Tnb0);

  // pass 0: score only          (layer-1 tables)
  // pass 1: score + Q=ego1(f32) (layer-1 tables), then build layer-2 tables
  // pass 2: score only          (layer-2 tables)
  // pass 3: mean output -> o1   (layer-2 tables; final A-update dead in reference)
  for (int pass = 0; pass < 4; ++pass) {
    const ushort4* Pb  = (pass < 2) ? Pb0 : Pb1;
    const ushort4* Tnb = (pass < 2) ? Tnb0 : Tnb1;
    const int mode = (pass == 1) ? 1 : (pass == 3) ? 2 : 0;
    deg_sm_k<<<(NNODES + 15) / 16, 256, 0, stream>>>(A, row_ptr, c, dv);
    prop_k<<<NNODES / 4, 256, 0, stream>>>(Pb, (float4*)ego1, dv, row_ptr, csr_t, c, A,
                                           Tnb, (const float4*)ego0, (const float4*)ego1,
                                           (float4*)o1, mode);
    if (pass == 1) {
      conv_k<<<2048, 256, 0, stream>>>((const float4*)ego1, Pb1);
      tanh_k<<<12500, 256, 0, stream>>>((const float4*)ego1, Tnb1);
    }
  }

  // duplicate (u_g, i_g) into the second output pair
  hipMemcpyAsync(o2, o1, sizeof(float) * (size_t)NNODES * EMBD,
                 hipMemcpyDeviceToDevice, stream);
}

// Round 7
// 1208.722 us; speedup vs baseline: 4.0632x; 1.0323x over previous
//
#include <hip/hip_runtime.h>
#include <cmath>

#define GS_LOOP(i, n) for (int i = blockIdx.x * blockDim.x + threadIdx.x; i < (n); i += gridDim.x * blockDim.x)

constexpr int NUSERS = 50000;
constexpr int NNODES = 100000;
constexpr int EMBD   = 128;
constexpr int NEDGE  = 2000000;
constexpr int NSCAN  = (NNODES + 1023) / 1024;   // 98

__device__ __forceinline__ float bf2f(unsigned short u) {
  union { unsigned int i; float f; } v; v.i = ((unsigned int)u) << 16; return v.f;
}
__device__ __forceinline__ unsigned short f2bf(float x) {
  union { float f; unsigned int i; } v; v.f = x;
  unsigned int r = v.i + 0x7FFFu + ((v.i >> 16) & 1u);   // round to nearest even
  return (unsigned short)(r >> 16);
}

// ---------------- init (row-oriented): ego0 + Pb0 + Tnb0 in one read ----------------
__global__ __launch_bounds__(256) void init_k(const float4* __restrict__ ue4,
                                              const float4* __restrict__ ie4,
                                              float4* __restrict__ ego0,
                                              ushort4* __restrict__ Pb0,
                                              ushort4* __restrict__ Tnb0) {
  const int j = threadIdx.x & 31;
  const int u = blockIdx.x * 8 + (threadIdx.x >> 5);
  if (u >= NNODES) return;
  const float4 y = (u < NUSERS) ? ue4[(size_t)u * 32 + j]
                                : ie4[(size_t)(u - NUSERS) * 32 + j];
  ego0[(size_t)u * 32 + j] = y;
  Pb0[(size_t)u * 32 + j] = make_ushort4(f2bf(y.x), f2bf(y.y), f2bf(y.z), f2bf(y.w));
  float ss = y.x * y.x + y.y * y.y + y.z * y.z + y.w * y.w;
  ss += __shfl_xor(ss, 1, 64);
  ss += __shfl_xor(ss, 2, 64);
  ss += __shfl_xor(ss, 4, 64);                  // 8-lane factor-group reduce
  const float inv = 1.f / fmaxf(sqrtf(ss), 1e-12f);
  Tnb0[(size_t)u * 32 + j] = make_ushort4(f2bf(tanhf(y.x * inv)), f2bf(tanhf(y.y * inv)),
                                          f2bf(tanhf(y.z * inv)), f2bf(tanhf(y.w * inv)));
}

// ---------------- CSR build ----------------
__global__ void hist_k(const int* __restrict__ h, int* __restrict__ counts,
                       float* __restrict__ A) {
  float4* A4 = (float4*)A;
  const float4 ones = make_float4(1.f, 1.f, 1.f, 1.f);
  GS_LOOP(e, NEDGE) { atomicAdd(&counts[h[e]], 1); A4[e] = ones; }
}

// hierarchical scan: per-block inclusive scan + block sums
__global__ __launch_bounds__(1024) void scan1_k(const int* __restrict__ counts,
                                                int* __restrict__ part,
                                                int* __restrict__ bsum) {
  __shared__ int wsum[16];
  const int tid = threadIdx.x, lane = tid & 63, wid = tid >> 6;
  const int i = blockIdx.x * 1024 + tid;
  int v = (i < NNODES) ? counts[i] : 0;
  #pragma unroll
  for (int off = 1; off < 64; off <<= 1) {
    int y = __shfl_up(v, off, 64);
    if (lane >= off) v += y;
  }
  if (lane == 63) wsum[wid] = v;
  __syncthreads();
  if (wid == 0) {
    int w = (lane < 16) ? wsum[lane] : 0;
    #pragma unroll
    for (int off = 1; off < 16; off <<= 1) {
      int y = __shfl_up(w, off, 64);
      if (lane >= off) w += y;
    }
    if (lane < 16) wsum[lane] = w;
  }
  __syncthreads();
  const int incl = v + (wid ? wsum[wid - 1] : 0);
  if (i < NNODES) part[i] = incl;
  if (tid == 1023) bsum[blockIdx.x] = incl;
}

__global__ __launch_bounds__(128) void scan2_k(const int* __restrict__ bsum,
                                               int* __restrict__ boff) {
  __shared__ int s0[128], s1[128];
  const int tid = threadIdx.x;
  s0[tid] = (tid < NSCAN) ? bsum[tid] : 0;
  __syncthreads();
  int* a = s0; int* b = s1;
  for (int off = 1; off < 128; off <<= 1) {
    const int val = a[tid] + ((tid >= off) ? a[tid - off] : 0);
    b[tid] = val;
    __syncthreads();
    int* tmp = a; a = b; b = tmp;
  }
  boff[tid] = (tid == 0) ? 0 : a[tid - 1];
}

__global__ __launch_bounds__(1024) void scan3_k(const int* __restrict__ part,
                                                const int* __restrict__ boff,
                                                int* __restrict__ row_ptr) {
  const int i = blockIdx.x * 1024 + threadIdx.x;
  if (i < NNODES) row_ptr[i + 1] = part[i] + boff[blockIdx.x];
  if (i == 0) row_ptr[0] = 0;
}

// edge identity irrelevant downstream (A lives in CSR order): store only t
__global__ void fill_k(const int* __restrict__ h, const int* __restrict__ t,
                       const int* __restrict__ row_ptr, int* __restrict__ cur,
                       int* __restrict__ csr_t) {
  GS_LOOP(e, NEDGE) {
    int u = h[e];
    int pos = row_ptr[u] + atomicAdd(&cur[u], 1);
    csr_t[pos] = t[e];
  }
}

// ---------------- per-pass: softmax(A)->c (csr order) + d_inv, 16 lanes/node ----------------
__global__ __launch_bounds__(256) void deg_sm_k(const float* __restrict__ A,
                                                const int* __restrict__ row_ptr,
                                                float* __restrict__ c,
                                                float* __restrict__ dv) {
  const float4* A4 = (const float4*)A;
  float4* c4 = (float4*)c;
  const int g = threadIdx.x >> 4;
  const int lane16 = threadIdx.x & 15;
  const int u = blockIdx.x * 16 + g;
  if (u >= NNODES) return;
  const int beg = row_ptr[u], end = row_ptr[u + 1];
  float4 acc = make_float4(0.f, 0.f, 0.f, 0.f);
  for (int p = beg + lane16; p < end; p += 16) {
    float4 a = A4[p];
    float m = fmaxf(fmaxf(a.x, a.y), fmaxf(a.z, a.w));
    float e0 = __expf(a.x - m), e1 = __expf(a.y - m);
    float e2 = __expf(a.z - m), e3 = __expf(a.w - m);
    float inv = 1.f / (e0 + e1 + e2 + e3);
    float4 s = make_float4(e0 * inv, e1 * inv, e2 * inv, e3 * inv);
    c4[p] = s;
    acc.x += s.x; acc.y += s.y; acc.z += s.z; acc.w += s.w;
  }
  #pragma unroll
  for (int m = 1; m < 16; m <<= 1) {
    acc.x += __shfl_xor(acc.x, m, 64);
    acc.y += __shfl_xor(acc.y, m, 64);
    acc.z += __shfl_xor(acc.z, m, 64);
    acc.w += __shfl_xor(acc.w, m, 64);
  }
  if (lane16 == 0)
    ((float4*)dv)[u] = make_float4(rsqrtf(fmaxf(acc.x, 1e-12f)),
                                   rsqrtf(fmaxf(acc.y, 1e-12f)),
                                   rsqrtf(fmaxf(acc.z, 1e-12f)),
                                   rsqrtf(fmaxf(acc.w, 1e-12f)));
}

// ---------------- fused propagate + score update (wave per node, bf16 gathers) ----------------
// mode: 0 = score only; 1 = score + write Q(f32) + Pb1/Tnb1 tables; 2 = mean output to o1
__global__ __launch_bounds__(256) void prop_k(
    const ushort4* __restrict__ Pb4, float4* __restrict__ Q4,
    const float* __restrict__ dv, const int* __restrict__ row_ptr,
    const int* __restrict__ csr_t, const float* __restrict__ c,
    float* __restrict__ A, const ushort4* __restrict__ Tnb4,
    const float4* __restrict__ e0_4, const float4* __restrict__ e1_4,
    float4* __restrict__ o1_4, ushort4* __restrict__ Pb1w,
    ushort4* __restrict__ Tnb1w, int mode) {
  const int u = blockIdx.x * 4 + (threadIdx.x >> 6);
  const int l = threadIdx.x & 63;
  const int half = l >> 5;     // which of 2 edges per iteration
  const int j = l & 31;        // float4 column
  const int f = j >> 3;        // factor
  const int beg = row_ptr[u], end = row_ptr[u + 1];

  // loop 1: x[u] = d_inv[u] * sum_p c[p][f] * d_inv[t_p][f] * Pb[t_p]
  float4 acc = make_float4(0.f, 0.f, 0.f, 0.f);
  int p = beg + half;
  for (; p + 14 < end; p += 16) {              // manual unroll x8: 8 row gathers in flight
    const int t0 = csr_t[p],      t1 = csr_t[p + 2];
    const int t2 = csr_t[p + 4],  t3 = csr_t[p + 6];
    const int t4 = csr_t[p + 8],  t5 = csr_t[p + 10];
    const int t6 = csr_t[p + 12], t7 = csr_t[p + 14];
    const ushort4 y0 = Pb4[(size_t)t0 * 32 + j];
    const ushort4 y1 = Pb4[(size_t)t1 * 32 + j];
    const ushort4 y2 = Pb4[(size_t)t2 * 32 + j];
    const ushort4 y3 = Pb4[(size_t)t3 * 32 + j];
    const ushort4 y4 = Pb4[(size_t)t4 * 32 + j];
    const ushort4 y5 = Pb4[(size_t)t5 * 32 + j];
    const ushort4 y6 = Pb4[(size_t)t6 * 32 + j];
    const ushort4 y7 = Pb4[(size_t)t7 * 32 + j];
    const float c0 = c[(size_t)p * 4 + f]        * dv[t0 * 4 + f];
    const float c1 = c[(size_t)(p + 2) * 4 + f]  * dv[t1 * 4 + f];
    const float c2 = c[(size_t)(p + 4) * 4 + f]  * dv[t2 * 4 + f];
    const float c3 = c[(size_t)(p + 6) * 4 + f]  * dv[t3 * 4 + f];
    const float c4_ = c[(size_t)(p + 8) * 4 + f] * dv[t4 * 4 + f];
    const float c5 = c[(size_t)(p + 10) * 4 + f] * dv[t5 * 4 + f];
    const float c6 = c[(size_t)(p + 12) * 4 + f] * dv[t6 * 4 + f];
    const float c7 = c[(size_t)(p + 14) * 4 + f] * dv[t7 * 4 + f];
    acc.x += c0 * bf2f(y0.x) + c1 * bf2f(y1.x) + c2 * bf2f(y2.x) + c3 * bf2f(y3.x)
           + c4_ * bf2f(y4.x) + c5 * bf2f(y5.x) + c6 * bf2f(y6.x) + c7 * bf2f(y7.x);
    acc.y += c0 * bf2f(y0.y) + c1 * bf2f(y1.y) + c2 * bf2f(y2.y) + c3 * bf2f(y3.y)
           + c4_ * bf2f(y4.y) + c5 * bf2f(y5.y) + c6 * bf2f(y6.y) + c7 * bf2f(y7.y);
    acc.z += c0 * bf2f(y0.z) + c1 * bf2f(y1.z) + c2 * bf2f(y2.z) + c3 * bf2f(y3.z)
           + c4_ * bf2f(y4.z) + c5 * bf2f(y5.z) + c6 * bf2f(y6.z) + c7 * bf2f(y7.z);
    acc.w += c0 * bf2f(y0.w) + c1 * bf2f(y1.w) + c2 * bf2f(y2.w) + c3 * bf2f(y3.w)
           + c4_ * bf2f(y4.w) + c5 * bf2f(y5.w) + c6 * bf2f(y6.w) + c7 * bf2f(y7.w);
  }
  for (; p < end; p += 2) {                    // tail
    const int tn = csr_t[p];
    const float cf = c[(size_t)p * 4 + f] * dv[tn * 4 + f];
    const ushort4 y = Pb4[(size_t)tn * 32 + j];
    acc.x += cf * bf2f(y.x); acc.y += cf * bf2f(y.y);
    acc.z += cf * bf2f(y.z); acc.w += cf * bf2f(y.w);
  }
  acc.x += __shfl_xor(acc.x, 32, 64);
  acc.y += __shfl_xor(acc.y, 32, 64);
  acc.z += __shfl_xor(acc.z, 32, 64);
  acc.w += __shfl_xor(acc.w, 32, 64);
  const float du = dv[u * 4 + f];
  const float4 x = make_float4(acc.x * du, acc.y * du, acc.z * du, acc.w * du);

  if (mode == 2) {                             // final pass: write mean(e0,e1,x) to o1
    if (half == 0) {
      const float4 a = e0_4[(size_t)u * 32 + j];
      const float4 b = e1_4[(size_t)u * 32 + j];
      o1_4[(size_t)u * 32 + j] = make_float4((a.x + b.x + x.x) * (1.f / 3.f),
                                             (a.y + b.y + x.y) * (1.f / 3.f),
                                             (a.z + b.z + x.z) * (1.f / 3.f),
                                             (a.w + b.w + x.w) * (1.f / 3.f));
    }
    return;
  }
  if (mode == 1 && half == 0) {
    Q4[(size_t)u * 32 + j] = x;
    Pb1w[(size_t)u * 32 + j] = make_ushort4(f2bf(x.x), f2bf(x.y), f2bf(x.z), f2bf(x.w));
  }

  // chunk l2-norm of x (8-lane factor group)
  float ss = x.x * x.x + x.y * x.y + x.z * x.z + x.w * x.w;
  ss += __shfl_xor(ss, 1, 64);
  ss += __shfl_xor(ss, 2, 64);
  ss += __shfl_xor(ss, 4, 64);
  const float inv = 1.f / fmaxf(sqrtf(ss), 1e-12f);
  const float4 xn = make_float4(x.x * inv, x.y * inv, x.z * inv, x.w * inv);
  if (mode == 1 && half == 0)
    Tnb1w[(size_t)u * 32 + j] = make_ushort4(f2bf(tanhf(xn.x)), f2bf(tanhf(xn.y)),
                                             f2bf(tanhf(xn.z)), f2bf(tanhf(xn.w)));

  // loop 2: A[p][f] += dot(xn_chunk, Tnb[t]_chunk)  (sequential A writes, no atomics)
  int q = beg + half;
  for (; q + 6 < end; q += 8) {                // manual unroll x4
    const int t0 = csr_t[q],     t1 = csr_t[q + 2];
    const int t2 = csr_t[q + 4], t3 = csr_t[q + 6];
    const ushort4 b0 = Tnb4[(size_t)t0 * 32 + j];
    const ushort4 b1 = Tnb4[(size_t)t1 * 32 + j];
    const ushort4 b2 = Tnb4[(size_t)t2 * 32 + j];
    const ushort4 b3 = Tnb4[(size_t)t3 * 32 + j];
    float s0 = xn.x * bf2f(b0.x) + xn.y * bf2f(b0.y) + xn.z * bf2f(b0.z) + xn.w * bf2f(b0.w);
    float s1 = xn.x * bf2f(b1.x) + xn.y * bf2f(b1.y) + xn.z * bf2f(b1.z) + xn.w * bf2f(b1.w);
    float s2 = xn.x * bf2f(b2.x) + xn.y * bf2f(b2.y) + xn.z * bf2f(b2.z) + xn.w * bf2f(b2.w);
    float s3 = xn.x * bf2f(b3.x) + xn.y * bf2f(b3.y) + xn.z * bf2f(b3.z) + xn.w * bf2f(b3.w);
    #pragma unroll
    for (int m = 1; m < 8; m <<= 1) {
      s0 += __shfl_xor(s0, m, 64); s1 += __shfl_xor(s1, m, 64);
      s2 += __shfl_xor(s2, m, 64); s3 += __shfl_xor(s3, m, 64);
    }
    if ((j & 7) == 0) {
      A[(size_t)q * 4 + f] += s0;
      A[(size_t)(q + 2) * 4 + f] += s1;
      A[(size_t)(q + 4) * 4 + f] += s2;
      A[(size_t)(q + 6) * 4 + f] += s3;
    }
  }
  for (; q < end; q += 2) {                    // tail
    const int tn = csr_t[q];
    const ushort4 tb = Tnb4[(size_t)tn * 32 + j];
    float s = xn.x * bf2f(tb.x) + xn.y * bf2f(tb.y) + xn.z * bf2f(tb.z) + xn.w * bf2f(tb.w);
    s += __shfl_xor(s, 1, 64);
    s += __shfl_xor(s, 2, 64);
    s += __shfl_xor(s, 4, 64);
    if ((j & 7) == 0) A[(size_t)q * 4 + f] += s;
  }
}

extern "C" void kernel_launch(void* const* d_in, const int* in_sizes, int n_in,
                              void* d_out, int out_size, void* d_ws, size_t ws_size,
                              hipStream_t stream) {
  const float* ue = (const float*)d_in[0];
  const float* ie = (const float*)d_in[1];
  const int* h = (const int*)d_in[2];
  const int* t = (const int*)d_in[3];
  float* out = (float*)d_out;
  char* ws = (char*)d_ws;

  size_t off = 0;
  auto alloc = [&](size_t bytes) -> void* {
    void* p = ws + off;
    off += (bytes + 255) & ~size_t(255);
    return p;
  };
  float* ego0  = (float*)alloc(sizeof(float) * (size_t)NNODES * EMBD);  // 51.2 MB
  float* ego1  = (float*)alloc(sizeof(float) * (size_t)NNODES * EMBD);  // 51.2 MB
  float* A     = (float*)alloc(sizeof(float) * 4 * (size_t)NEDGE);      // 32  MB (CSR order)
  float* c     = (float*)alloc(sizeof(float) * 4 * (size_t)NEDGE);      // 32  MB (CSR order)
  float* dv    = (float*)alloc(sizeof(float) * NNODES * 4);             // 1.6 MB
  int* row_ptr = (int*)alloc(sizeof(int) * (NNODES + 1));
  int* cur     = (int*)alloc(sizeof(int) * NNODES);
  int* part    = (int*)alloc(sizeof(int) * NNODES);                     // 0.4 MB
  int* bsum    = (int*)alloc(sizeof(int) * 128);
  int* boff    = (int*)alloc(sizeof(int) * 128);
  int* csr_t   = (int*)alloc(sizeof(int) * NEDGE);                      // 8 MB

  // bf16 gather tables live in d_out (each half = 51.2 MB = Pb(25.6) + Tnb(25.6)).
  // Layer-1 tables in o1 (dead by pass 3, which overwrites o1);
  // layer-2 tables in o2 (read during pass 3; o2 refilled by the final d2d copy).
  float* o1 = out;
  float* o2 = out + (size_t)NNODES * EMBD;
  ushort4* Pb0  = (ushort4*)o1;
  ushort4* Tnb0 = (ushort4*)((char*)o1 + sizeof(unsigned short) * (size_t)NNODES * EMBD);
  ushort4* Pb1  = (ushort4*)o2;
  ushort4* Tnb1 = (ushort4*)((char*)o2 + sizeof(unsigned short) * (size_t)NNODES * EMBD);

  // setup (once per call)
  init_k<<<(NNODES + 7) / 8, 256, 0, stream>>>((const float4*)ue, (const float4*)ie,
                                               (float4*)ego0, Pb0, Tnb0);
  hipMemsetAsync(cur, 0, sizeof(int) * NNODES, stream);
  hist_k<<<2048, 256, 0, stream>>>(h, cur, A);
  scan1_k<<<NSCAN, 1024, 0, stream>>>(cur, part, bsum);
  scan2_k<<<1, 128, 0, stream>>>(bsum, boff);
  scan3_k<<<NSCAN, 1024, 0, stream>>>(part, boff, row_ptr);
  hipMemsetAsync(cur, 0, sizeof(int) * NNODES, stream);
  fill_k<<<2048, 256, 0, stream>>>(h, t, row_ptr, cur, csr_t);

  // pass 0: score only                       (layer-1 tables)
  // pass 1: score + Q=ego1 + Pb1/Tnb1 tables (layer-1 tables)
  // pass 2: score only                       (layer-2 tables)
  // pass 3: mean output -> o1                (layer-2 tables; final A-update dead)
  for (int pass = 0; pass < 4; ++pass) {
    const ushort4* Pb  = (pass < 2) ? Pb0 : Pb1;
    const ushort4* Tnb = (pass < 2) ? Tnb0 : Tnb1;
    const int mode = (pass == 1) ? 1 : (pass == 3) ? 2 : 0;
    deg_sm_k<<<(NNODES + 15) / 16, 256, 0, stream>>>(A, row_ptr, c, dv);
    prop_k<<<NNODES / 4, 256, 0, stream>>>(Pb, (float4*)ego1, dv, row_ptr, csr_t, c, A,
                                           Tnb, (const float4*)ego0, (const float4*)ego1,
                                           (float4*)o1, Pb1, Tnb1, mode);
  }

  // duplicate (u_g, i_g) into the second output pair
  hipMemcpyAsync(o2, o1, sizeof(float) * (size_t)NNODES * EMBD,
                 hipMemcpyDeviceToDevice, stream);
}